// Round 8
// baseline (566.629 us; speedup 1.0000x reference)
//
#include <hip/hip_runtime.h>
#include <hip/hip_bf16.h>

// ---------------------------------------------------------------------------
// PointCloudExtractor: T-Net -> transform -> multi-radius topK gather -> MLP
// B=8 N=2048 K=64 TU=256 U=512, blocks 512->512, 512->256, 256->170
// Pipeline: init(memset+convw_t+tnet1), tnet2, topk, mlp_k (all 5 layers)
// R2: topk insertion shift via DPP WF_SR1
// R6: fused init; topk 512-thr blocks
// R7: MLP row-fused in LDS (verified passing)
// R8: DIAGNOSTIC ROUND -- init_k, tnet2_k, mlp_k each dispatched TWICE
//     (all are idempotent: pure recompute; outF zeroing happens pre-mlp;
//     mlp's atomicMax re-applies identical values). The measured
//     total' - total = t_init + t_tnet2 + t_mlp, resolving whether the
//     ~300us residual lives in these kernels or in harness dispatches.
// ---------------------------------------------------------------------------

#define BN_SCALE 0.99950037468777f   // float32(1/sqrt(1+1e-3))

typedef short short8 __attribute__((ext_vector_type(8)));
typedef short sh4 __attribute__((ext_vector_type(4)));
typedef float floatx4 __attribute__((ext_vector_type(4)));

__device__ inline short f2bf(float x) {
    __hip_bfloat16 h = __float2bfloat16(x);
    return *reinterpret_cast<short*>(&h);
}
__device__ inline float bf2f(short s) {
    return __uint_as_float(((unsigned)(unsigned short)s) << 16);
}

// workspace layout (bytes)
#define OFF_FEATS 0                      // bf16 [16384,576]  18,874,368
#define OFF_W     18874368
#define OFF_C1WT  (OFF_W)                // bf16 [512][576]
#define OFF_RWT   (OFF_C1WT + 589824)    // bf16 [512][512]
#define OFF_B1WT  (OFF_RWT + 524288)     // bf16 [512][512]
#define OFF_B2WT  (OFF_B1WT + 524288)    // bf16 [256][512]
#define OFF_B3WT  (OFF_B2WT + 262144)    // bf16 [256][256] (rows>=170 zero)
#define OFF_PTS   (OFF_B3WT + 131072)    // f32 [8,2048,3]
#define OFF_PART  (OFF_PTS + 196608)     // f32 [8][8][256] tnet1 partial max

// ---- fused init: weight transpose (blocks 0..247) + T-Net layer1 partial
//      max (blocks 248..311) + d_out zero-init (block 312) -----------------
__global__ __launch_bounds__(256)
void init_k(const float* __restrict__ c1w, const float* __restrict__ rw,
            const float* __restrict__ b1w, const float* __restrict__ b2w,
            const float* __restrict__ b3w,
            short* __restrict__ c1wT, short* __restrict__ rwT,
            short* __restrict__ b1wT, short* __restrict__ b2wT,
            short* __restrict__ b3wT,
            const float* __restrict__ points, const float* __restrict__ tw,
            const float* __restrict__ tb, const float* __restrict__ tg1,
            const float* __restrict__ tbt1, float* __restrict__ part,
            float* __restrict__ outF, int out_n) {
    __shared__ float smem[64 * 65];
    const int bid = blockIdx.x;
    if (bid < 248) {
        float (*tile)[65] = (float(*)[65])smem;
        const float* src; short* dst; int K, N, t;
        if (bid < 72)       { src = c1w; dst = c1wT; K = 576; N = 512; t = bid; }
        else if (bid < 136) { src = rw;  dst = rwT;  K = 512; N = 512; t = bid - 72; }
        else if (bid < 200) { src = b1w; dst = b1wT; K = 512; N = 512; t = bid - 136; }
        else if (bid < 232) { src = b2w; dst = b2wT; K = 512; N = 256; t = bid - 200; }
        else                { src = b3w; dst = b3wT; K = 256; N = 170; t = bid - 232; }
        int ktiles = K >> 6;
        int k0 = (t % ktiles) * 64, n0 = (t / ktiles) * 64;
        int tx = threadIdx.x & 63, ty = threadIdx.x >> 6;
#pragma unroll
        for (int p = 0; p < 16; p++) {
            int r = p * 4 + ty;
            int n = n0 + tx;
            tile[r][tx] = (n < N) ? src[(size_t)(k0 + r) * N + n] : 0.f;
        }
        __syncthreads();
#pragma unroll
        for (int p = 0; p < 16; p++) {
            int r = p * 4 + ty;
            dst[(size_t)(n0 + r) * K + k0 + tx] = f2bf(tile[tx][r]);
        }
    } else if (bid < 312) {
        float* spts = smem;   // [768]
        const int t2 = bid - 248;
        const int chunk = t2 & 7, b = t2 >> 3;
        const int u = threadIdx.x;
        const float* pb = points + ((size_t)b * 2048 + chunk * 256) * 3;
        for (int i = u; i < 768; i += 256) spts[i] = pb[i];
        const float w0 = tw[u], w1 = tw[256 + u], w2 = tw[512 + u];
        const float bi = tb[u];
        const float gs = tg1[u] * BN_SCALE, bt = tbt1[u];
        __syncthreads();
        float m = 0.f;  // relu outputs >= 0
        for (int nn = 0; nn < 256; nn++) {
            float v = spts[nn * 3] * w0 + spts[nn * 3 + 1] * w1 +
                      spts[nn * 3 + 2] * w2 + bi;
            v = fmaxf(v * gs + bt, 0.f);
            m = fmaxf(m, v);
        }
        part[((b * 8 + chunk) << 8) + u] = m;
    } else {
        for (int i = threadIdx.x; i < out_n; i += 256) outF[i] = 0.f;
    }
}

// ---- T-Net dense layers + transform pts (latency-parallel matvecs) ---------
__global__ __launch_bounds__(1024)
void tnet2_k(const float* __restrict__ points, const float* __restrict__ part,
             const float* __restrict__ td1w, const float* __restrict__ td1b,
             const float* __restrict__ tg2, const float* __restrict__ tbt2,
             const float* __restrict__ td2w, const float* __restrict__ td2b,
             float* __restrict__ pts_out) {
    __shared__ float sx[256], sp[4][256], sx2[256], sp2[9][32], sT[9];
    const int b = blockIdx.x;
    const int tid = threadIdx.x;
    if (tid < 256) {
        float m = 0.f;
#pragma unroll
        for (int c = 0; c < 8; c++) m = fmaxf(m, part[((b * 8 + c) << 8) + tid]);
        sx[tid] = m;
    }
    __syncthreads();
    {
        int t = tid & 255, g = tid >> 8;
        float s = 0.f;
#pragma unroll 8
        for (int i = 0; i < 64; i++) {
            int v = g * 64 + i;
            s += sx[v] * td1w[v * 256 + t];
        }
        sp[g][t] = s;
    }
    __syncthreads();
    if (tid < 256) {
        float s = td1b[tid] + sp[0][tid] + sp[1][tid] + sp[2][tid] + sp[3][tid];
        sx2[tid] = fmaxf(s * (tg2[tid] * BN_SCALE) + tbt2[tid], 0.f);
    }
    __syncthreads();
    if (tid < 288) {
        int j = tid / 32, vg = tid & 31;
        float s = 0.f;
#pragma unroll
        for (int i = 0; i < 8; i++) {
            int v = vg * 8 + i;
            s += sx2[v] * td2w[v * 9 + j];
        }
        sp2[j][vg] = s;
    }
    __syncthreads();
    if (tid < 9) {
        float s = td2b[tid];
        for (int vg = 0; vg < 32; vg++) s += sp2[tid][vg];
        sT[tid] = s;
    }
    __syncthreads();
    for (int n = tid; n < 2048; n += 1024) {
        size_t idx = ((size_t)b * 2048 + n) * 3;
        float p0 = points[idx], p1 = points[idx + 1], p2 = points[idx + 2];
        pts_out[idx]     = p0 * sT[0] + p1 * sT[3] + p2 * sT[6];
        pts_out[idx + 1] = p0 * sT[1] + p1 * sT[4] + p2 * sT[7];
        pts_out[idx + 2] = p0 * sT[2] + p1 * sT[5] + p2 * sT[8];
    }
}

// ---- top-K ball query + gather -> feats bf16 (R6-verified) -----------------
__device__ inline unsigned dpp_shr1(unsigned v) {
    return (unsigned)__builtin_amdgcn_update_dpp(0, (int)v, 0x138 /*WF_SR1*/,
                                                 0xF, 0xF, false);
}

__device__ inline void ins_one(unsigned& llo, unsigned& lhi, unsigned vlo,
                               unsigned vhi, int lane) {
    unsigned long long lv = ((unsigned long long)lhi << 32) | llo;
    unsigned long long vv = ((unsigned long long)vhi << 32) | vlo;
    unsigned long long ltm = __ballot(lv < vv);
    if (ltm) {
        int p = __builtin_ctzll(ltm);
        unsigned uplo = dpp_shr1(llo);
        unsigned uphi = dpp_shr1(lhi);
        if (lane >= p) {
            llo = (lane == p) ? vlo : uplo;
            lhi = (lane == p) ? vhi : uphi;
        }
    }
}

__device__ inline void run_q(unsigned& llo, unsigned& lhi, unsigned long long& th,
                             unsigned klo, unsigned khi, unsigned long long qual,
                             int lane) {
    do {
        int src = __builtin_ctzll(qual);
        qual &= qual - 1;
        unsigned vlo = (unsigned)__builtin_amdgcn_readlane((int)klo, src);
        unsigned vhi = (unsigned)__builtin_amdgcn_readlane((int)khi, src);
        ins_one(llo, lhi, vlo, vhi, lane);
    } while (qual);
    th = ((unsigned long long)(unsigned)__builtin_amdgcn_readlane((int)lhi, 63) << 32)
         | (unsigned)__builtin_amdgcn_readlane((int)llo, 63);
}

__device__ inline void init_radius(bool in, unsigned nb, unsigned klo, int lane,
                                   unsigned& llo, unsigned& lhi,
                                   unsigned long long& th) {
    unsigned long long inm = __ballot(in);
    int S = 64 - __builtin_popcountll(inm);
    int mbI = __builtin_amdgcn_mbcnt_hi((unsigned)(inm >> 32),
              __builtin_amdgcn_mbcnt_lo((unsigned)inm, 0));
    int mbS = lane - mbI;
    int dst = in ? (S + mbI) : mbS;
    llo = (unsigned)__builtin_amdgcn_ds_permute(dst << 2, in ? 0 : (int)klo);
    lhi = 0;
    if (inm) {
        do {
            int src = __builtin_ctzll(inm);
            inm &= inm - 1;
            unsigned vlo = (unsigned)__builtin_amdgcn_readlane((int)klo, src);
            unsigned vhi = (unsigned)__builtin_amdgcn_readlane((int)nb, src);
            ins_one(llo, lhi, vlo, vhi, lane);
        } while (inm);
    }
    th = ((unsigned long long)(unsigned)__builtin_amdgcn_readlane((int)lhi, 63) << 32)
         | (unsigned)__builtin_amdgcn_readlane((int)llo, 63);
}

__global__ __launch_bounds__(512)
void topk_feats_k(const float* __restrict__ pts, const float* __restrict__ noise,
                  short* __restrict__ feats) {
    __shared__ float sxp[2048], syp[2048], szp[2048];
    const int b = blockIdx.y;
    const int tid = threadIdx.x;
    const int lane = tid & 63;
    const int wave = tid >> 6;
    const int n = blockIdx.x * 8 + wave;
    const float* nrow = noise + ((size_t)b * 2048 + n) * 2048;
    float ncur = nrow[lane];
    float nnxt = nrow[64 + lane];
    for (int i = tid; i < 2048; i += 512) {
        size_t p = ((size_t)b * 2048 + i) * 3;
        sxp[i] = pts[p];
        syp[i] = pts[p + 1];
        szp[i] = pts[p + 2];
    }
    __syncthreads();
    const float qx = sxp[n], qy = syp[n], qz = szp[n];

    unsigned L0lo, L0hi, L1lo, L1hi, L2lo, L2hi;
    unsigned long long th0, th1, th2;
    {
        float dx = qx - sxp[lane], dy = qy - syp[lane], dz = qz - szp[lane];
        float d = sqrtf(dx * dx + dy * dy + dz * dz);
        unsigned nb = __float_as_uint(ncur);
        unsigned klo = 2047 - lane;
        init_radius(d <= 0.1f, nb, klo, lane, L0lo, L0hi, th0);
        init_radius(d <= 0.3f, nb, klo, lane, L1lo, L1hi, th1);
        init_radius(d <= 0.7f, nb, klo, lane, L2lo, L2hi, th2);
    }
    for (int base = 64; base < 2048; base += 64) {
        float cur = nnxt;
        if (base + 64 < 2048) nnxt = nrow[base + 64 + lane];
        const int j = base + lane;
        float dx = qx - sxp[j], dy = qy - syp[j], dz = qz - szp[j];
        float d = sqrtf(dx * dx + dy * dy + dz * dz);
        unsigned nb = __float_as_uint(cur);
        unsigned klo = 2047 - j;
        unsigned k0hi = (d <= 0.1f) ? nb : 0u;
        unsigned k1hi = (d <= 0.3f) ? nb : 0u;
        unsigned k2hi = (d <= 0.7f) ? nb : 0u;
        unsigned long long key0 = ((unsigned long long)k0hi << 32) | klo;
        unsigned long long key1 = ((unsigned long long)k1hi << 32) | klo;
        unsigned long long key2 = ((unsigned long long)k2hi << 32) | klo;
        unsigned long long q0 = __ballot(key0 > th0);
        unsigned long long q1 = __ballot(key1 > th1);
        unsigned long long q2 = __ballot(key2 > th2);
        if (q0) run_q(L0lo, L0hi, th0, klo, k0hi, q0, lane);
        if (q1) run_q(L1lo, L1hi, th1, klo, k1hi, q1, lane);
        if (q2) run_q(L2lo, L2hi, th2, klo, k2hi, q2, lane);
    }
    size_t basef = ((size_t)b * 2048 + n) * 576 + (size_t)lane * 9;
    int j0 = 2047 - (int)(L0lo & 0x7FFu);
    int j1 = 2047 - (int)(L1lo & 0x7FFu);
    int j2 = 2047 - (int)(L2lo & 0x7FFu);
    feats[basef + 0] = f2bf(sxp[j0]);
    feats[basef + 1] = f2bf(syp[j0]);
    feats[basef + 2] = f2bf(szp[j0]);
    feats[basef + 3] = f2bf(sxp[j1]);
    feats[basef + 4] = f2bf(syp[j1]);
    feats[basef + 5] = f2bf(szp[j1]);
    feats[basef + 6] = f2bf(sxp[j2]);
    feats[basef + 7] = f2bf(syp[j2]);
    feats[basef + 8] = f2bf(szp[j2]);
}

// ---- row-fused MLP (R7 structure, unchanged) -------------------------------
template <int NF, int EPI, int BSRC, int K>
__device__ __forceinline__ void layer(
    const short* __restrict__ WT, const short* __restrict__ gfeats,
    const short* actIn, short* actOut,
    const float* __restrict__ bias, const float* __restrict__ gamma,
    const float* __restrict__ beta, float* __restrict__ outF,
    int m0, int Nact) {
    const int tid = threadIdx.x;
    const int lane = tid & 63;
    const int wave = tid >> 6;
    const int lr = lane & 15, lq = lane >> 4;
    const int n0w = wave * (NF * 16);

    floatx4 acc[NF][4];
#pragma unroll
    for (int i = 0; i < NF; i++)
#pragma unroll
        for (int j = 0; j < 4; j++) acc[i][j] = (floatx4){0.f, 0.f, 0.f, 0.f};

#pragma unroll 2
    for (int k0 = 0; k0 < K; k0 += 32) {
        short8 af[NF], bf[4];
#pragma unroll
        for (int i = 0; i < NF; i++)
            af[i] = *(const short8*)(WT + (size_t)(n0w + i * 16 + lr) * K + k0 + lq * 8);
        if (BSRC == 0) {
#pragma unroll
            for (int j = 0; j < 4; j++)
                bf[j] = *(const short8*)(gfeats + (size_t)(m0 + j * 16 + lr) * 576 + k0 + lq * 8);
        } else {
#pragma unroll
            for (int j = 0; j < 4; j++) {
                int m = j * 16 + lr;
                bf[j] = *(const short8*)((const char*)actIn + m * 1024 +
                                         ((k0 * 2 + lq * 16) ^ ((m & 7) << 4)));
            }
        }
#pragma unroll
        for (int i = 0; i < NF; i++)
#pragma unroll
            for (int j = 0; j < 4; j++)
                acc[i][j] = __builtin_amdgcn_mfma_f32_16x16x32_bf16(af[i], bf[j],
                                                                    acc[i][j], 0, 0, 0);
    }

    if (EPI == 2) {
        const int bb = m0 >> 11;
#pragma unroll
        for (int i = 0; i < NF; i++) {
            int nb = n0w + i * 16 + lq * 4;
            float bi[4], gs[4], bt[4], cm[4];
#pragma unroll
            for (int rg = 0; rg < 4; rg++) {
                int n = nb + rg;
                bool ok = n < Nact;
                bi[rg] = ok ? bias[n] : 0.f;
                gs[rg] = ok ? gamma[n] * BN_SCALE : 0.f;
                bt[rg] = ok ? beta[n] : 0.f;
                cm[rg] = 0.f;
            }
#pragma unroll
            for (int j = 0; j < 4; j++)
#pragma unroll
                for (int rg = 0; rg < 4; rg++) {
                    float v = fmaxf((acc[i][j][rg] + bi[rg]) * gs[rg] + bt[rg], 0.f);
                    cm[rg] = fmaxf(cm[rg], v);
                }
#pragma unroll
            for (int rg = 0; rg < 4; rg++) {
                cm[rg] = fmaxf(cm[rg], __shfl_xor(cm[rg], 1));
                cm[rg] = fmaxf(cm[rg], __shfl_xor(cm[rg], 2));
                cm[rg] = fmaxf(cm[rg], __shfl_xor(cm[rg], 4));
                cm[rg] = fmaxf(cm[rg], __shfl_xor(cm[rg], 8));
            }
            if (lr == 0) {
#pragma unroll
                for (int rg = 0; rg < 4; rg++) {
                    int n = nb + rg;
                    if (n < Nact)
                        atomicMax((unsigned*)&outF[bb * 170 + n],
                                  __float_as_uint(cm[rg]));
                }
            }
        }
    } else {
#pragma unroll
        for (int i = 0; i < NF; i++) {
            int nb = n0w + i * 16 + lq * 4;
            floatx4 bi = *(const floatx4*)(bias + nb);
            floatx4 gs = {0.f, 0.f, 0.f, 0.f}, bt = {0.f, 0.f, 0.f, 0.f};
            if (EPI == 0) {
                gs = *(const floatx4*)(gamma + nb);
                bt = *(const floatx4*)(beta + nb);
            }
#pragma unroll
            for (int j = 0; j < 4; j++) {
                int m = j * 16 + lr;
                int off = m * 1024 + ((nb * 2) ^ ((m & 7) << 4));
                sh4 pk;
                if (EPI == 1) {
                    sh4 rs = *(const sh4*)((const char*)actIn + off);
#pragma unroll
                    for (int rg = 0; rg < 4; rg++)
                        pk[rg] = f2bf(acc[i][j][rg] + bi[rg] + bf2f(rs[rg]));
                } else {
#pragma unroll
                    for (int rg = 0; rg < 4; rg++)
                        pk[rg] = f2bf(fmaxf((acc[i][j][rg] + bi[rg]) *
                                            (gs[rg] * BN_SCALE) + bt[rg], 0.f));
                }
                *(sh4*)((char*)actOut + off) = pk;
            }
        }
    }
}

__global__ __launch_bounds__(256, 1)
void mlp_k(const short* __restrict__ feats,
           const short* __restrict__ c1wT, const short* __restrict__ rwT,
           const short* __restrict__ b1wT, const short* __restrict__ b2wT,
           const short* __restrict__ b3wT,
           const float* __restrict__ c1b, const float* __restrict__ g1,
           const float* __restrict__ be1, const float* __restrict__ rb,
           const float* __restrict__ b1b, const float* __restrict__ b1g,
           const float* __restrict__ b1be,
           const float* __restrict__ b2b, const float* __restrict__ b2g,
           const float* __restrict__ b2be,
           const float* __restrict__ b3b, const float* __restrict__ b3g,
           const float* __restrict__ b3be, float* __restrict__ outF) {
    __shared__ __align__(16) short actA[64 * 512];
    __shared__ __align__(16) short actB[64 * 512];
    const int m0 = blockIdx.x * 64;

    layer<8, 0, 0, 576>(c1wT, feats, nullptr, actA, c1b, g1, be1, nullptr, m0, 512);
    __syncthreads();
    layer<8, 1, 1, 512>(rwT, nullptr, actA, actB, rb, nullptr, nullptr, nullptr, m0, 512);
    __syncthreads();
    layer<8, 0, 1, 512>(b1wT, nullptr, actB, actA, b1b, b1g, b1be, nullptr, m0, 512);
    __syncthreads();
    layer<4, 0, 1, 512>(b2wT, nullptr, actA, actB, b2b, b2g, b2be, nullptr, m0, 256);
    __syncthreads();
    layer<4, 2, 1, 256>(b3wT, nullptr, actB, nullptr, b3b, b3g, b3be, outF, m0, 170);
}

extern "C" void kernel_launch(void* const* d_in, const int* in_sizes, int n_in,
                              void* d_out, int out_size, void* d_ws, size_t ws_size,
                              hipStream_t stream) {
    const float* points = (const float*)d_in[0];
    const float* noise  = (const float*)d_in[1];
    const float* tw   = (const float*)d_in[2];
    const float* tb   = (const float*)d_in[3];
    const float* tg1  = (const float*)d_in[4];
    const float* tbt1 = (const float*)d_in[5];
    const float* td1w = (const float*)d_in[6];
    const float* td1b = (const float*)d_in[7];
    const float* tg2  = (const float*)d_in[8];
    const float* tbt2 = (const float*)d_in[9];
    const float* td2w = (const float*)d_in[10];
    const float* td2b = (const float*)d_in[11];
    const float* c1w  = (const float*)d_in[12];
    const float* c1b  = (const float*)d_in[13];
    const float* g1   = (const float*)d_in[14];
    const float* be1  = (const float*)d_in[15];
    const float* rw   = (const float*)d_in[16];
    const float* rb   = (const float*)d_in[17];
    const float* b1w  = (const float*)d_in[18];
    const float* b1b  = (const float*)d_in[19];
    const float* b1g  = (const float*)d_in[20];
    const float* b1be = (const float*)d_in[21];
    const float* b2w  = (const float*)d_in[22];
    const float* b2b  = (const float*)d_in[23];
    const float* b2g  = (const float*)d_in[24];
    const float* b2be = (const float*)d_in[25];
    const float* b3w  = (const float*)d_in[26];
    const float* b3b  = (const float*)d_in[27];
    const float* b3g  = (const float*)d_in[28];
    const float* b3be = (const float*)d_in[29];

    char* ws = (char*)d_ws;
    short* feats = (short*)(ws + OFF_FEATS);
    short* c1wT  = (short*)(ws + OFF_C1WT);
    short* rwT   = (short*)(ws + OFF_RWT);
    short* b1wT  = (short*)(ws + OFF_B1WT);
    short* b2wT  = (short*)(ws + OFF_B2WT);
    short* b3wT  = (short*)(ws + OFF_B3WT);
    float* pts   = (float*)(ws + OFF_PTS);
    float* part  = (float*)(ws + OFF_PART);
    float* outF  = (float*)d_out;

    // R8 diagnostic: init/tnet2/mlp dispatched twice (idempotent).
    // total' - 450 = t_init + t_tnet2 + t_mlp.
    init_k<<<313, 256, 0, stream>>>(c1w, rw, b1w, b2w, b3w,
                                    c1wT, rwT, b1wT, b2wT, b3wT,
                                    points, tw, tb, tg1, tbt1, part,
                                    outF, out_size);
    init_k<<<313, 256, 0, stream>>>(c1w, rw, b1w, b2w, b3w,
                                    c1wT, rwT, b1wT, b2wT, b3wT,
                                    points, tw, tb, tg1, tbt1, part,
                                    outF, out_size);
    tnet2_k<<<8, 1024, 0, stream>>>(points, part, td1w, td1b, tg2, tbt2,
                                    td2w, td2b, pts);
    tnet2_k<<<8, 1024, 0, stream>>>(points, part, td1w, td1b, tg2, tbt2,
                                    td2w, td2b, pts);
    topk_feats_k<<<dim3(256, 8), 512, 0, stream>>>(pts, noise, feats);
    mlp_k<<<256, 256, 0, stream>>>(feats, c1wT, rwT, b1wT, b2wT, b3wT,
                                   c1b, g1, be1, rb, b1b, b1g, b1be,
                                   b2b, b2g, b2be, b3b, b3g, b3be, outF);
    mlp_k<<<256, 256, 0, stream>>>(feats, c1wT, rwT, b1wT, b2wT, b3wT,
                                   c1b, g1, be1, rb, b1b, b1g, b1be,
                                   b2b, b2g, b2be, b3b, b3g, b3be, outF);
}

// Round 9
// 475.573 us; speedup vs baseline: 1.1915x; 1.1915x over previous
//
#include <hip/hip_runtime.h>
#include <hip/hip_bf16.h>

// ---------------------------------------------------------------------------
// PointCloudExtractor: T-Net -> transform -> multi-radius topK gather -> MLP
// B=8 N=2048 K=64 TU=256 U=512, blocks 512->512, 512->256, 256->170
// Pipeline (4 dispatches): init(transpose+zero), tnet12, topk, mlp
// R2: topk insertion shift via DPP WF_SR1
// R8 decomposition: fixed harness ~195us, topk ~139us, mid-section ~110us.
// R9: (a) mlp in-place single 64KB act buffer -> 2 blocks/CU (2 waves/SIMD,
//     was 1); fragment-in-regs + pre-read residual + sync-then-write makes
//     in-place safe. (b) tnet1+tnet2 merged into one 8-block kernel.
// ---------------------------------------------------------------------------

#define BN_SCALE 0.99950037468777f   // float32(1/sqrt(1+1e-3))

typedef short short8 __attribute__((ext_vector_type(8)));
typedef short sh4 __attribute__((ext_vector_type(4)));
typedef float floatx4 __attribute__((ext_vector_type(4)));

__device__ inline short f2bf(float x) {
    __hip_bfloat16 h = __float2bfloat16(x);
    return *reinterpret_cast<short*>(&h);
}
__device__ inline float bf2f(short s) {
    return __uint_as_float(((unsigned)(unsigned short)s) << 16);
}

// workspace layout (bytes)
#define OFF_FEATS 0                      // bf16 [16384,576]  18,874,368
#define OFF_W     18874368
#define OFF_C1WT  (OFF_W)                // bf16 [512][576]
#define OFF_RWT   (OFF_C1WT + 589824)    // bf16 [512][512]
#define OFF_B1WT  (OFF_RWT + 524288)     // bf16 [512][512]
#define OFF_B2WT  (OFF_B1WT + 524288)    // bf16 [256][512]
#define OFF_B3WT  (OFF_B2WT + 262144)    // bf16 [256][256] (rows>=170 zero)
#define OFF_PTS   (OFF_B3WT + 131072)    // f32 [8,2048,3]

// ---- init: weight transpose (blocks 0..247) + d_out zero (block 248) ------
__global__ __launch_bounds__(256)
void init_k(const float* __restrict__ c1w, const float* __restrict__ rw,
            const float* __restrict__ b1w, const float* __restrict__ b2w,
            const float* __restrict__ b3w,
            short* __restrict__ c1wT, short* __restrict__ rwT,
            short* __restrict__ b1wT, short* __restrict__ b2wT,
            short* __restrict__ b3wT,
            float* __restrict__ outF, int out_n) {
    __shared__ float tile[64][65];
    const int bid = blockIdx.x;
    if (bid < 248) {
        const float* src; short* dst; int K, N, t;
        if (bid < 72)       { src = c1w; dst = c1wT; K = 576; N = 512; t = bid; }
        else if (bid < 136) { src = rw;  dst = rwT;  K = 512; N = 512; t = bid - 72; }
        else if (bid < 200) { src = b1w; dst = b1wT; K = 512; N = 512; t = bid - 136; }
        else if (bid < 232) { src = b2w; dst = b2wT; K = 512; N = 256; t = bid - 200; }
        else                { src = b3w; dst = b3wT; K = 256; N = 170; t = bid - 232; }
        int ktiles = K >> 6;
        int k0 = (t % ktiles) * 64, n0 = (t / ktiles) * 64;
        int tx = threadIdx.x & 63, ty = threadIdx.x >> 6;
#pragma unroll
        for (int p = 0; p < 16; p++) {
            int r = p * 4 + ty;
            int n = n0 + tx;
            tile[r][tx] = (n < N) ? src[(size_t)(k0 + r) * N + n] : 0.f;
        }
        __syncthreads();
#pragma unroll
        for (int p = 0; p < 16; p++) {
            int r = p * 4 + ty;
            dst[(size_t)(n0 + r) * K + k0 + tx] = f2bf(tile[tx][r]);
        }
    } else {
        for (int i = threadIdx.x; i < out_n; i += 256) outF[i] = 0.f;
    }
}

// ---- full T-Net per batch: layer1+maxpool+dense1+dense2+transform ----------
// one 1024-thread block per batch; points staged once in LDS.
__global__ __launch_bounds__(1024)
void tnet12_k(const float* __restrict__ points,
              const float* __restrict__ tw, const float* __restrict__ tb,
              const float* __restrict__ tg1, const float* __restrict__ tbt1,
              const float* __restrict__ td1w, const float* __restrict__ td1b,
              const float* __restrict__ tg2, const float* __restrict__ tbt2,
              const float* __restrict__ td2w, const float* __restrict__ td2b,
              float* __restrict__ pts_out) {
    __shared__ float spts[2048 * 3];                 // 24 KB
    __shared__ float sx[256], sp[4][256], sx2[256], sp2[9][32], sT[9];
    const int b = blockIdx.x;
    const int tid = threadIdx.x;
    const float* pb = points + (size_t)b * 2048 * 3;
    for (int i = tid; i < 6144; i += 1024) spts[i] = pb[i];
    __syncthreads();
    {   // layer1 + partial max: unit u, point-chunk c (512 points each)
        int u = tid & 255, c = tid >> 8;
        const float w0 = tw[u], w1 = tw[256 + u], w2 = tw[512 + u];
        const float bi = tb[u];
        const float gs = tg1[u] * BN_SCALE, bt = tbt1[u];
        const float* spc = spts + c * 512 * 3;
        float m = 0.f;  // relu outputs >= 0
        for (int nn = 0; nn < 512; nn++) {
            float v = spc[nn * 3] * w0 + spc[nn * 3 + 1] * w1 +
                      spc[nn * 3 + 2] * w2 + bi;
            m = fmaxf(m, fmaxf(v * gs + bt, 0.f));
        }
        sp[c][u] = m;
    }
    __syncthreads();
    if (tid < 256)
        sx[tid] = fmaxf(fmaxf(sp[0][tid], sp[1][tid]),
                        fmaxf(sp[2][tid], sp[3][tid]));
    __syncthreads();
    {   // dense1: 256x256, v split 4 ways
        int t = tid & 255, g = tid >> 8;
        float s = 0.f;
#pragma unroll 8
        for (int i = 0; i < 64; i++) {
            int v = g * 64 + i;
            s += sx[v] * td1w[v * 256 + t];
        }
        sp[g][t] = s;
    }
    __syncthreads();
    if (tid < 256) {
        float s = td1b[tid] + sp[0][tid] + sp[1][tid] + sp[2][tid] + sp[3][tid];
        sx2[tid] = fmaxf(s * (tg2[tid] * BN_SCALE) + tbt2[tid], 0.f);
    }
    __syncthreads();
    if (tid < 288) {   // dense2: 256->9, v split 32 ways
        int j = tid / 32, vg = tid & 31;
        float s = 0.f;
#pragma unroll
        for (int i = 0; i < 8; i++) {
            int v = vg * 8 + i;
            s += sx2[v] * td2w[v * 9 + j];
        }
        sp2[j][vg] = s;
    }
    __syncthreads();
    if (tid < 9) {
        float s = td2b[tid];
        for (int vg = 0; vg < 32; vg++) s += sp2[tid][vg];
        sT[tid] = s;
    }
    __syncthreads();
    for (int n = tid; n < 2048; n += 1024) {
        float p0 = spts[n * 3], p1 = spts[n * 3 + 1], p2 = spts[n * 3 + 2];
        size_t idx = ((size_t)b * 2048 + n) * 3;
        pts_out[idx]     = p0 * sT[0] + p1 * sT[3] + p2 * sT[6];
        pts_out[idx + 1] = p0 * sT[1] + p1 * sT[4] + p2 * sT[7];
        pts_out[idx + 2] = p0 * sT[2] + p1 * sT[5] + p2 * sT[8];
    }
}

// ---- top-K ball query + gather -> feats bf16 (R6-verified, unchanged) ------
__device__ inline unsigned dpp_shr1(unsigned v) {
    return (unsigned)__builtin_amdgcn_update_dpp(0, (int)v, 0x138 /*WF_SR1*/,
                                                 0xF, 0xF, false);
}

__device__ inline void ins_one(unsigned& llo, unsigned& lhi, unsigned vlo,
                               unsigned vhi, int lane) {
    unsigned long long lv = ((unsigned long long)lhi << 32) | llo;
    unsigned long long vv = ((unsigned long long)vhi << 32) | vlo;
    unsigned long long ltm = __ballot(lv < vv);
    if (ltm) {
        int p = __builtin_ctzll(ltm);
        unsigned uplo = dpp_shr1(llo);
        unsigned uphi = dpp_shr1(lhi);
        if (lane >= p) {
            llo = (lane == p) ? vlo : uplo;
            lhi = (lane == p) ? vhi : uphi;
        }
    }
}

__device__ inline void run_q(unsigned& llo, unsigned& lhi, unsigned long long& th,
                             unsigned klo, unsigned khi, unsigned long long qual,
                             int lane) {
    do {
        int src = __builtin_ctzll(qual);
        qual &= qual - 1;
        unsigned vlo = (unsigned)__builtin_amdgcn_readlane((int)klo, src);
        unsigned vhi = (unsigned)__builtin_amdgcn_readlane((int)khi, src);
        ins_one(llo, lhi, vlo, vhi, lane);
    } while (qual);
    th = ((unsigned long long)(unsigned)__builtin_amdgcn_readlane((int)lhi, 63) << 32)
         | (unsigned)__builtin_amdgcn_readlane((int)llo, 63);
}

__device__ inline void init_radius(bool in, unsigned nb, unsigned klo, int lane,
                                   unsigned& llo, unsigned& lhi,
                                   unsigned long long& th) {
    unsigned long long inm = __ballot(in);
    int S = 64 - __builtin_popcountll(inm);
    int mbI = __builtin_amdgcn_mbcnt_hi((unsigned)(inm >> 32),
              __builtin_amdgcn_mbcnt_lo((unsigned)inm, 0));
    int mbS = lane - mbI;
    int dst = in ? (S + mbI) : mbS;
    llo = (unsigned)__builtin_amdgcn_ds_permute(dst << 2, in ? 0 : (int)klo);
    lhi = 0;
    if (inm) {
        do {
            int src = __builtin_ctzll(inm);
            inm &= inm - 1;
            unsigned vlo = (unsigned)__builtin_amdgcn_readlane((int)klo, src);
            unsigned vhi = (unsigned)__builtin_amdgcn_readlane((int)nb, src);
            ins_one(llo, lhi, vlo, vhi, lane);
        } while (inm);
    }
    th = ((unsigned long long)(unsigned)__builtin_amdgcn_readlane((int)lhi, 63) << 32)
         | (unsigned)__builtin_amdgcn_readlane((int)llo, 63);
}

__global__ __launch_bounds__(512)
void topk_feats_k(const float* __restrict__ pts, const float* __restrict__ noise,
                  short* __restrict__ feats) {
    __shared__ float sxp[2048], syp[2048], szp[2048];
    const int b = blockIdx.y;
    const int tid = threadIdx.x;
    const int lane = tid & 63;
    const int wave = tid >> 6;
    const int n = blockIdx.x * 8 + wave;
    const float* nrow = noise + ((size_t)b * 2048 + n) * 2048;
    float ncur = nrow[lane];
    float nnxt = nrow[64 + lane];
    for (int i = tid; i < 2048; i += 512) {
        size_t p = ((size_t)b * 2048 + i) * 3;
        sxp[i] = pts[p];
        syp[i] = pts[p + 1];
        szp[i] = pts[p + 2];
    }
    __syncthreads();
    const float qx = sxp[n], qy = syp[n], qz = szp[n];

    unsigned L0lo, L0hi, L1lo, L1hi, L2lo, L2hi;
    unsigned long long th0, th1, th2;
    {
        float dx = qx - sxp[lane], dy = qy - syp[lane], dz = qz - szp[lane];
        float d = sqrtf(dx * dx + dy * dy + dz * dz);
        unsigned nb = __float_as_uint(ncur);
        unsigned klo = 2047 - lane;
        init_radius(d <= 0.1f, nb, klo, lane, L0lo, L0hi, th0);
        init_radius(d <= 0.3f, nb, klo, lane, L1lo, L1hi, th1);
        init_radius(d <= 0.7f, nb, klo, lane, L2lo, L2hi, th2);
    }
    for (int base = 64; base < 2048; base += 64) {
        float cur = nnxt;
        if (base + 64 < 2048) nnxt = nrow[base + 64 + lane];
        const int j = base + lane;
        float dx = qx - sxp[j], dy = qy - syp[j], dz = qz - szp[j];
        float d = sqrtf(dx * dx + dy * dy + dz * dz);
        unsigned nb = __float_as_uint(cur);
        unsigned klo = 2047 - j;
        unsigned k0hi = (d <= 0.1f) ? nb : 0u;
        unsigned k1hi = (d <= 0.3f) ? nb : 0u;
        unsigned k2hi = (d <= 0.7f) ? nb : 0u;
        unsigned long long key0 = ((unsigned long long)k0hi << 32) | klo;
        unsigned long long key1 = ((unsigned long long)k1hi << 32) | klo;
        unsigned long long key2 = ((unsigned long long)k2hi << 32) | klo;
        unsigned long long q0 = __ballot(key0 > th0);
        unsigned long long q1 = __ballot(key1 > th1);
        unsigned long long q2 = __ballot(key2 > th2);
        if (q0) run_q(L0lo, L0hi, th0, klo, k0hi, q0, lane);
        if (q1) run_q(L1lo, L1hi, th1, klo, k1hi, q1, lane);
        if (q2) run_q(L2lo, L2hi, th2, klo, k2hi, q2, lane);
    }
    size_t basef = ((size_t)b * 2048 + n) * 576 + (size_t)lane * 9;
    int j0 = 2047 - (int)(L0lo & 0x7FFu);
    int j1 = 2047 - (int)(L1lo & 0x7FFu);
    int j2 = 2047 - (int)(L2lo & 0x7FFu);
    feats[basef + 0] = f2bf(sxp[j0]);
    feats[basef + 1] = f2bf(syp[j0]);
    feats[basef + 2] = f2bf(szp[j0]);
    feats[basef + 3] = f2bf(sxp[j1]);
    feats[basef + 4] = f2bf(syp[j1]);
    feats[basef + 5] = f2bf(szp[j1]);
    feats[basef + 6] = f2bf(sxp[j2]);
    feats[basef + 7] = f2bf(syp[j2]);
    feats[basef + 8] = f2bf(szp[j2]);
}

// ---- row-fused MLP, in-place single act buffer (64 KB -> 2 blocks/CU) ------
// One block = 64-row stripe through all 5 layers. Single LDS act buffer
// [64][512] bf16, XOR-swizzled (byte ^= (row&7)<<4). In-place safety:
// each layer computes its full output fragment in registers (and pre-reads
// the residual fragment for EPI1), then __syncthreads (all reads retired),
// then writes, then __syncthreads before the next layer reads.
// Operand-swapped MFMA: A = weight rows (global/L2), B = act rows (LDS).
template <int NF, int EPI, int BSRC, int K>
__device__ __forceinline__ void layer(
    const short* __restrict__ WT, const short* __restrict__ gfeats,
    short* actS,
    const float* __restrict__ bias, const float* __restrict__ gamma,
    const float* __restrict__ beta, float* __restrict__ outF,
    int m0, int Nact) {
    const int tid = threadIdx.x;
    const int lane = tid & 63;
    const int wave = tid >> 6;
    const int lr = lane & 15, lq = lane >> 4;
    const int n0w = wave * (NF * 16);

    floatx4 acc[NF][4];
#pragma unroll
    for (int i = 0; i < NF; i++)
#pragma unroll
        for (int j = 0; j < 4; j++) acc[i][j] = (floatx4){0.f, 0.f, 0.f, 0.f};

#pragma unroll 2
    for (int k0 = 0; k0 < K; k0 += 32) {
        short8 af[NF], bf[4];
#pragma unroll
        for (int i = 0; i < NF; i++)
            af[i] = *(const short8*)(WT + (size_t)(n0w + i * 16 + lr) * K + k0 + lq * 8);
        if (BSRC == 0) {
#pragma unroll
            for (int j = 0; j < 4; j++)
                bf[j] = *(const short8*)(gfeats + (size_t)(m0 + j * 16 + lr) * 576 + k0 + lq * 8);
        } else {
#pragma unroll
            for (int j = 0; j < 4; j++) {
                int m = j * 16 + lr;
                bf[j] = *(const short8*)((const char*)actS + m * 1024 +
                                         ((k0 * 2 + lq * 16) ^ ((m & 7) << 4)));
            }
        }
#pragma unroll
        for (int i = 0; i < NF; i++)
#pragma unroll
            for (int j = 0; j < 4; j++)
                acc[i][j] = __builtin_amdgcn_mfma_f32_16x16x32_bf16(af[i], bf[j],
                                                                    acc[i][j], 0, 0, 0);
    }

    if (EPI == 2) {
        // read-only epilogue: col-max + atomicMax (no actS writes)
        const int bb = m0 >> 11;
#pragma unroll
        for (int i = 0; i < NF; i++) {
            int nb = n0w + i * 16 + lq * 4;
            float bi[4], gs[4], bt[4], cm[4];
#pragma unroll
            for (int rg = 0; rg < 4; rg++) {
                int n = nb + rg;
                bool ok = n < Nact;
                bi[rg] = ok ? bias[n] : 0.f;
                gs[rg] = ok ? gamma[n] * BN_SCALE : 0.f;
                bt[rg] = ok ? beta[n] : 0.f;
                cm[rg] = 0.f;
            }
#pragma unroll
            for (int j = 0; j < 4; j++)
#pragma unroll
                for (int rg = 0; rg < 4; rg++) {
                    float v = fmaxf((acc[i][j][rg] + bi[rg]) * gs[rg] + bt[rg], 0.f);
                    cm[rg] = fmaxf(cm[rg], v);
                }
#pragma unroll
            for (int rg = 0; rg < 4; rg++) {
                cm[rg] = fmaxf(cm[rg], __shfl_xor(cm[rg], 1));
                cm[rg] = fmaxf(cm[rg], __shfl_xor(cm[rg], 2));
                cm[rg] = fmaxf(cm[rg], __shfl_xor(cm[rg], 4));
                cm[rg] = fmaxf(cm[rg], __shfl_xor(cm[rg], 8));
            }
            if (lr == 0) {
#pragma unroll
                for (int rg = 0; rg < 4; rg++) {
                    int n = nb + rg;
                    if (n < Nact)
                        atomicMax((unsigned*)&outF[bb * 170 + n],
                                  __float_as_uint(cm[rg]));
                }
            }
        }
        return;
    }

    // pre-read residual fragments (EPI1) BEFORE the barrier
    sh4 rs[NF][4];
    if (EPI == 1) {
#pragma unroll
        for (int i = 0; i < NF; i++) {
            int nb = n0w + i * 16 + lq * 4;
#pragma unroll
            for (int j = 0; j < 4; j++) {
                int m = j * 16 + lr;
                rs[i][j] = *(const sh4*)((const char*)actS +
                                         m * 1024 + ((nb * 2) ^ ((m & 7) << 4)));
            }
        }
    }
    __syncthreads();   // all waves done READING actS for this layer

#pragma unroll
    for (int i = 0; i < NF; i++) {
        int nb = n0w + i * 16 + lq * 4;
        floatx4 bi = *(const floatx4*)(bias + nb);
        floatx4 gs = {0.f, 0.f, 0.f, 0.f}, bt = {0.f, 0.f, 0.f, 0.f};
        if (EPI == 0) {
            gs = *(const floatx4*)(gamma + nb);
            bt = *(const floatx4*)(beta + nb);
        }
#pragma unroll
        for (int j = 0; j < 4; j++) {
            int m = j * 16 + lr;
            int off = m * 1024 + ((nb * 2) ^ ((m & 7) << 4));
            sh4 pk;
            if (EPI == 1) {
#pragma unroll
                for (int rg = 0; rg < 4; rg++)
                    pk[rg] = f2bf(acc[i][j][rg] + bi[rg] + bf2f(rs[i][j][rg]));
            } else {
#pragma unroll
                for (int rg = 0; rg < 4; rg++)
                    pk[rg] = f2bf(fmaxf((acc[i][j][rg] + bi[rg]) *
                                        (gs[rg] * BN_SCALE) + bt[rg], 0.f));
            }
            *(sh4*)((char*)actS + off) = pk;
        }
    }
}

__global__ __launch_bounds__(256, 2)
void mlp_k(const short* __restrict__ feats,
           const short* __restrict__ c1wT, const short* __restrict__ rwT,
           const short* __restrict__ b1wT, const short* __restrict__ b2wT,
           const short* __restrict__ b3wT,
           const float* __restrict__ c1b, const float* __restrict__ g1,
           const float* __restrict__ be1, const float* __restrict__ rb,
           const float* __restrict__ b1b, const float* __restrict__ b1g,
           const float* __restrict__ b1be,
           const float* __restrict__ b2b, const float* __restrict__ b2g,
           const float* __restrict__ b2be,
           const float* __restrict__ b3b, const float* __restrict__ b3g,
           const float* __restrict__ b3be, float* __restrict__ outF) {
    __shared__ __align__(16) short actS[64 * 512];   // 64 KB
    const int m0 = blockIdx.x * 64;

    // L1: actS = relu(bn(feats @ c1wT))
    layer<8, 0, 0, 576>(c1wT, feats, actS, c1b, g1, be1, nullptr, m0, 512);
    __syncthreads();
    // L2: actS = actS + (actS @ rwT + rb)   (in-place, rs pre-read)
    layer<8, 1, 1, 512>(rwT, nullptr, actS, rb, nullptr, nullptr, nullptr, m0, 512);
    __syncthreads();
    // L3: actS = relu(bn(actS @ b1wT))
    layer<8, 0, 1, 512>(b1wT, nullptr, actS, b1b, b1g, b1be, nullptr, m0, 512);
    __syncthreads();
    // L4: actS[:, :256] = relu(bn(actS @ b2wT))
    layer<4, 0, 1, 512>(b2wT, nullptr, actS, b2b, b2g, b2be, nullptr, m0, 256);
    __syncthreads();
    // L5: out = colmax(relu(bn(actS[:, :256] @ b3wT)))
    layer<4, 2, 1, 256>(b3wT, nullptr, actS, b3b, b3g, b3be, outF, m0, 170);
}

extern "C" void kernel_launch(void* const* d_in, const int* in_sizes, int n_in,
                              void* d_out, int out_size, void* d_ws, size_t ws_size,
                              hipStream_t stream) {
    const float* points = (const float*)d_in[0];
    const float* noise  = (const float*)d_in[1];
    const float* tw   = (const float*)d_in[2];
    const float* tb   = (const float*)d_in[3];
    const float* tg1  = (const float*)d_in[4];
    const float* tbt1 = (const float*)d_in[5];
    const float* td1w = (const float*)d_in[6];
    const float* td1b = (const float*)d_in[7];
    const float* tg2  = (const float*)d_in[8];
    const float* tbt2 = (const float*)d_in[9];
    const float* td2w = (const float*)d_in[10];
    const float* td2b = (const float*)d_in[11];
    const float* c1w  = (const float*)d_in[12];
    const float* c1b  = (const float*)d_in[13];
    const float* g1   = (const float*)d_in[14];
    const float* be1  = (const float*)d_in[15];
    const float* rw   = (const float*)d_in[16];
    const float* rb   = (const float*)d_in[17];
    const float* b1w  = (const float*)d_in[18];
    const float* b1b  = (const float*)d_in[19];
    const float* b1g  = (const float*)d_in[20];
    const float* b1be = (const float*)d_in[21];
    const float* b2w  = (const float*)d_in[22];
    const float* b2b  = (const float*)d_in[23];
    const float* b2g  = (const float*)d_in[24];
    const float* b2be = (const float*)d_in[25];
    const float* b3w  = (const float*)d_in[26];
    const float* b3b  = (const float*)d_in[27];
    const float* b3g  = (const float*)d_in[28];
    const float* b3be = (const float*)d_in[29];

    char* ws = (char*)d_ws;
    short* feats = (short*)(ws + OFF_FEATS);
    short* c1wT  = (short*)(ws + OFF_C1WT);
    short* rwT   = (short*)(ws + OFF_RWT);
    short* b1wT  = (short*)(ws + OFF_B1WT);
    short* b2wT  = (short*)(ws + OFF_B2WT);
    short* b3wT  = (short*)(ws + OFF_B3WT);
    float* pts   = (float*)(ws + OFF_PTS);
    float* outF  = (float*)d_out;

    init_k<<<249, 256, 0, stream>>>(c1w, rw, b1w, b2w, b3w,
                                    c1wT, rwT, b1wT, b2wT, b3wT,
                                    outF, out_size);
    tnet12_k<<<8, 1024, 0, stream>>>(points, tw, tb, tg1, tbt1,
                                     td1w, td1b, tg2, tbt2, td2w, td2b, pts);
    topk_feats_k<<<dim3(256, 8), 512, 0, stream>>>(pts, noise, feats);
    mlp_k<<<256, 256, 0, stream>>>(feats, c1wT, rwT, b1wT, b2wT, b3wT,
                                   c1b, g1, be1, rb, b1b, b1g, b1be,
                                   b2b, b2g, b2be, b3b, b3g, b3be, outF);
}

// Round 10
// 427.945 us; speedup vs baseline: 1.3241x; 1.1113x over previous
//
#include <hip/hip_runtime.h>
#include <hip/hip_bf16.h>
#include <math.h>

// ---------------------------------------------------------------------------
// PointCloudExtractor: T-Net -> transform -> multi-radius topK gather -> MLP
// B=8 N=2048 K=64 TU=256 U=512, blocks 512->512, 512->256, 256->170
// Pipeline: init(memset+convw_t+tnet1), tnet2, topk, 5x gemm  [R6 structure]
// R2:  topk insertion shift via DPP WF_SR1
// R3:  gemm 2-phase double-buffered staging
// R6:  fused init; topk 512-thr blocks  (best verified: 437.0 us)
// R8:  decomposition: ~195us fixed harness, ~139 topk, ~85 gemms, ~18 rest
// R10: revert R7/R9 experiments; topk compares squared distance against
//      host-computed thresholds R = largest float < midpoint(r,next(r))^2
//      -- exactly equivalent to correctly-rounded sqrtf(s)<=r, removes the
//      precise-sqrt sequence (~8 VALU ops x 32 iters) from the hot loop.
// ---------------------------------------------------------------------------

#define BN_SCALE 0.99950037468777f   // float32(1/sqrt(1+1e-3))

typedef short short8 __attribute__((ext_vector_type(8)));
typedef float floatx4 __attribute__((ext_vector_type(4)));

typedef __attribute__((address_space(1))) const short gshort;
typedef __attribute__((address_space(3))) short lshort;

// workspace layout (bytes)
#define OFF_FEATS 0                      // bf16 [16384,576]  18,874,368 (region0)
#define OFF_R1    18874368               // region1 16,777,216: f1/f3 bf16 [16384,512]
#define OFF_W     (OFF_R1 + 16777216)
#define OFF_C1WT  (OFF_W)                // bf16 [512][576]
#define OFF_RWT   (OFF_C1WT + 589824)    // bf16 [512][512]
#define OFF_B1WT  (OFF_RWT + 524288)     // bf16 [512][512]
#define OFF_B2WT  (OFF_B1WT + 524288)    // bf16 [256][512]
#define OFF_B3WT  (OFF_B2WT + 262144)    // bf16 [256][256] (rows>=170 zero)
#define OFF_PTS   (OFF_B3WT + 131072)    // f32 [8,2048,3]
#define OFF_PART  (OFF_PTS + 196608)     // f32 [8][8][256] tnet1 partial max

__device__ inline short f2bf(float x) {
    __hip_bfloat16 h = __float2bfloat16(x);
    return *reinterpret_cast<short*>(&h);
}
__device__ inline float bf2f(short s) {
    return __uint_as_float(((unsigned)(unsigned short)s) << 16);
}

// ---- fused init: weight transpose (blocks 0..247) + T-Net layer1 partial
//      max (blocks 248..311) + d_out zero-init (block 312) -----------------
__global__ __launch_bounds__(256)
void init_k(const float* __restrict__ c1w, const float* __restrict__ rw,
            const float* __restrict__ b1w, const float* __restrict__ b2w,
            const float* __restrict__ b3w,
            short* __restrict__ c1wT, short* __restrict__ rwT,
            short* __restrict__ b1wT, short* __restrict__ b2wT,
            short* __restrict__ b3wT,
            const float* __restrict__ points, const float* __restrict__ tw,
            const float* __restrict__ tb, const float* __restrict__ tg1,
            const float* __restrict__ tbt1, float* __restrict__ part,
            float* __restrict__ outF, int out_n) {
    __shared__ float smem[64 * 65];
    const int bid = blockIdx.x;
    if (bid < 248) {
        float (*tile)[65] = (float(*)[65])smem;
        const float* src; short* dst; int K, N, t;
        if (bid < 72)       { src = c1w; dst = c1wT; K = 576; N = 512; t = bid; }
        else if (bid < 136) { src = rw;  dst = rwT;  K = 512; N = 512; t = bid - 72; }
        else if (bid < 200) { src = b1w; dst = b1wT; K = 512; N = 512; t = bid - 136; }
        else if (bid < 232) { src = b2w; dst = b2wT; K = 512; N = 256; t = bid - 200; }
        else                { src = b3w; dst = b3wT; K = 256; N = 170; t = bid - 232; }
        int ktiles = K >> 6;
        int k0 = (t % ktiles) * 64, n0 = (t / ktiles) * 64;
        int tx = threadIdx.x & 63, ty = threadIdx.x >> 6;
#pragma unroll
        for (int p = 0; p < 16; p++) {
            int r = p * 4 + ty;
            int n = n0 + tx;
            tile[r][tx] = (n < N) ? src[(size_t)(k0 + r) * N + n] : 0.f;
        }
        __syncthreads();
#pragma unroll
        for (int p = 0; p < 16; p++) {
            int r = p * 4 + ty;
            dst[(size_t)(n0 + r) * K + k0 + tx] = f2bf(tile[tx][r]);
        }
    } else if (bid < 312) {
        float* spts = smem;   // [768]
        const int t2 = bid - 248;
        const int chunk = t2 & 7, b = t2 >> 3;
        const int u = threadIdx.x;
        const float* pb = points + ((size_t)b * 2048 + chunk * 256) * 3;
        for (int i = u; i < 768; i += 256) spts[i] = pb[i];
        const float w0 = tw[u], w1 = tw[256 + u], w2 = tw[512 + u];
        const float bi = tb[u];
        const float gs = tg1[u] * BN_SCALE, bt = tbt1[u];
        __syncthreads();
        float m = 0.f;  // relu outputs >= 0
        for (int nn = 0; nn < 256; nn++) {
            float v = spts[nn * 3] * w0 + spts[nn * 3 + 1] * w1 +
                      spts[nn * 3 + 2] * w2 + bi;
            v = fmaxf(v * gs + bt, 0.f);
            m = fmaxf(m, v);
        }
        part[((b * 8 + chunk) << 8) + u] = m;
    } else {
        for (int i = threadIdx.x; i < out_n; i += 256) outF[i] = 0.f;
    }
}

// ---- T-Net dense layers + transform pts (latency-parallel matvecs) ---------
__global__ __launch_bounds__(1024)
void tnet2_k(const float* __restrict__ points, const float* __restrict__ part,
             const float* __restrict__ td1w, const float* __restrict__ td1b,
             const float* __restrict__ tg2, const float* __restrict__ tbt2,
             const float* __restrict__ td2w, const float* __restrict__ td2b,
             float* __restrict__ pts_out) {
    __shared__ float sx[256], sp[4][256], sx2[256], sp2[9][32], sT[9];
    const int b = blockIdx.x;
    const int tid = threadIdx.x;
    if (tid < 256) {
        float m = 0.f;
#pragma unroll
        for (int c = 0; c < 8; c++) m = fmaxf(m, part[((b * 8 + c) << 8) + tid]);
        sx[tid] = m;
    }
    __syncthreads();
    {
        int t = tid & 255, g = tid >> 8;
        float s = 0.f;
#pragma unroll 8
        for (int i = 0; i < 64; i++) {
            int v = g * 64 + i;
            s += sx[v] * td1w[v * 256 + t];
        }
        sp[g][t] = s;
    }
    __syncthreads();
    if (tid < 256) {
        float s = td1b[tid] + sp[0][tid] + sp[1][tid] + sp[2][tid] + sp[3][tid];
        sx2[tid] = fmaxf(s * (tg2[tid] * BN_SCALE) + tbt2[tid], 0.f);
    }
    __syncthreads();
    if (tid < 288) {
        int j = tid / 32, vg = tid & 31;
        float s = 0.f;
#pragma unroll
        for (int i = 0; i < 8; i++) {
            int v = vg * 8 + i;
            s += sx2[v] * td2w[v * 9 + j];
        }
        sp2[j][vg] = s;
    }
    __syncthreads();
    if (tid < 9) {
        float s = td2b[tid];
        for (int vg = 0; vg < 32; vg++) s += sp2[tid][vg];
        sT[tid] = s;
    }
    __syncthreads();
    for (int n = tid; n < 2048; n += 1024) {
        size_t idx = ((size_t)b * 2048 + n) * 3;
        float p0 = points[idx], p1 = points[idx + 1], p2 = points[idx + 2];
        pts_out[idx]     = p0 * sT[0] + p1 * sT[3] + p2 * sT[6];
        pts_out[idx + 1] = p0 * sT[1] + p1 * sT[4] + p2 * sT[7];
        pts_out[idx + 2] = p0 * sT[2] + p1 * sT[5] + p2 * sT[8];
    }
}

// ---- top-K ball query + gather -> feats bf16 -------------------------------
// R10: distance test uses squared distance vs host-computed threshold
// (exactly equivalent to correctly-rounded sqrtf(s) <= r). Insertion via
// DPP WF_SR1 (0x138: lane n <- lane n-1), R2-verified.
__device__ inline unsigned dpp_shr1(unsigned v) {
    return (unsigned)__builtin_amdgcn_update_dpp(0, (int)v, 0x138 /*WF_SR1*/,
                                                 0xF, 0xF, false);
}

__device__ inline void ins_one(unsigned& llo, unsigned& lhi, unsigned vlo,
                               unsigned vhi, int lane) {
    unsigned long long lv = ((unsigned long long)lhi << 32) | llo;
    unsigned long long vv = ((unsigned long long)vhi << 32) | vlo;
    unsigned long long ltm = __ballot(lv < vv);
    if (ltm) {
        int p = __builtin_ctzll(ltm);
        unsigned uplo = dpp_shr1(llo);
        unsigned uphi = dpp_shr1(lhi);
        if (lane >= p) {
            llo = (lane == p) ? vlo : uplo;
            lhi = (lane == p) ? vhi : uphi;
        }
    }
}

__device__ inline void run_q(unsigned& llo, unsigned& lhi, unsigned long long& th,
                             unsigned klo, unsigned khi, unsigned long long qual,
                             int lane) {
    do {
        int src = __builtin_ctzll(qual);
        qual &= qual - 1;
        unsigned vlo = (unsigned)__builtin_amdgcn_readlane((int)klo, src);
        unsigned vhi = (unsigned)__builtin_amdgcn_readlane((int)khi, src);
        ins_one(llo, lhi, vlo, vhi, lane);
    } while (qual);
    th = ((unsigned long long)(unsigned)__builtin_amdgcn_readlane((int)lhi, 63) << 32)
         | (unsigned)__builtin_amdgcn_readlane((int)llo, 63);
}

__device__ inline void init_radius(bool in, unsigned nb, unsigned klo, int lane,
                                   unsigned& llo, unsigned& lhi,
                                   unsigned long long& th) {
    unsigned long long inm = __ballot(in);
    int S = 64 - __builtin_popcountll(inm);
    int mbI = __builtin_amdgcn_mbcnt_hi((unsigned)(inm >> 32),
              __builtin_amdgcn_mbcnt_lo((unsigned)inm, 0));
    int mbS = lane - mbI;
    int dst = in ? (S + mbI) : mbS;
    llo = (unsigned)__builtin_amdgcn_ds_permute(dst << 2, in ? 0 : (int)klo);
    lhi = 0;
    if (inm) {
        do {
            int src = __builtin_ctzll(inm);
            inm &= inm - 1;
            unsigned vlo = (unsigned)__builtin_amdgcn_readlane((int)klo, src);
            unsigned vhi = (unsigned)__builtin_amdgcn_readlane((int)nb, src);
            ins_one(llo, lhi, vlo, vhi, lane);
        } while (inm);
    }
    th = ((unsigned long long)(unsigned)__builtin_amdgcn_readlane((int)lhi, 63) << 32)
         | (unsigned)__builtin_amdgcn_readlane((int)llo, 63);
}

__global__ __launch_bounds__(512)
void topk_feats_k(const float* __restrict__ pts, const float* __restrict__ noise,
                  short* __restrict__ feats,
                  float r0s, float r1s, float r2s) {
    __shared__ float sxp[2048], syp[2048], szp[2048];
    const int b = blockIdx.y;
    const int tid = threadIdx.x;
    const int lane = tid & 63;
    const int wave = tid >> 6;
    const int n = blockIdx.x * 8 + wave;
    const float* nrow = noise + ((size_t)b * 2048 + n) * 2048;
    float ncur = nrow[lane];
    float nnxt = nrow[64 + lane];
    for (int i = tid; i < 2048; i += 512) {
        size_t p = ((size_t)b * 2048 + i) * 3;
        sxp[i] = pts[p];
        syp[i] = pts[p + 1];
        szp[i] = pts[p + 2];
    }
    __syncthreads();
    const float qx = sxp[n], qy = syp[n], qz = szp[n];

    unsigned L0lo, L0hi, L1lo, L1hi, L2lo, L2hi;
    unsigned long long th0, th1, th2;
    {
        float dx = qx - sxp[lane], dy = qy - syp[lane], dz = qz - szp[lane];
        float s = dx * dx + dy * dy + dz * dz;
        unsigned nb = __float_as_uint(ncur);
        unsigned klo = 2047 - lane;
        init_radius(s <= r0s, nb, klo, lane, L0lo, L0hi, th0);
        init_radius(s <= r1s, nb, klo, lane, L1lo, L1hi, th1);
        init_radius(s <= r2s, nb, klo, lane, L2lo, L2hi, th2);
    }
    for (int base = 64; base < 2048; base += 64) {
        float cur = nnxt;
        if (base + 64 < 2048) nnxt = nrow[base + 64 + lane];
        const int j = base + lane;
        float dx = qx - sxp[j], dy = qy - syp[j], dz = qz - szp[j];
        float s = dx * dx + dy * dy + dz * dz;
        unsigned nb = __float_as_uint(cur);
        unsigned klo = 2047 - j;
        unsigned k0hi = (s <= r0s) ? nb : 0u;
        unsigned k1hi = (s <= r1s) ? nb : 0u;
        unsigned k2hi = (s <= r2s) ? nb : 0u;
        unsigned long long key0 = ((unsigned long long)k0hi << 32) | klo;
        unsigned long long key1 = ((unsigned long long)k1hi << 32) | klo;
        unsigned long long key2 = ((unsigned long long)k2hi << 32) | klo;
        unsigned long long q0 = __ballot(key0 > th0);
        unsigned long long q1 = __ballot(key1 > th1);
        unsigned long long q2 = __ballot(key2 > th2);
        if (q0) run_q(L0lo, L0hi, th0, klo, k0hi, q0, lane);
        if (q1) run_q(L1lo, L1hi, th1, klo, k1hi, q1, lane);
        if (q2) run_q(L2lo, L2hi, th2, klo, k2hi, q2, lane);
    }
    size_t basef = ((size_t)b * 2048 + n) * 576 + (size_t)lane * 9;
    int j0 = 2047 - (int)(L0lo & 0x7FFu);
    int j1 = 2047 - (int)(L1lo & 0x7FFu);
    int j2 = 2047 - (int)(L2lo & 0x7FFu);
    feats[basef + 0] = f2bf(sxp[j0]);
    feats[basef + 1] = f2bf(syp[j0]);
    feats[basef + 2] = f2bf(szp[j0]);
    feats[basef + 3] = f2bf(sxp[j1]);
    feats[basef + 4] = f2bf(syp[j1]);
    feats[basef + 5] = f2bf(szp[j1]);
    feats[basef + 6] = f2bf(sxp[j2]);
    feats[basef + 7] = f2bf(syp[j2]);
    feats[basef + 8] = f2bf(szp[j2]);
}

// ---- bf16 MFMA GEMM, 128x128 tile, 4 waves, 2-phase double-buffered --------
// A [M,K] bf16 row-major, BT [Npad,K] bf16. LDS linear (global_load_lds
// writes wave-uniform base + lane*16). Issue next tile's global_load_lds
// BEFORE computing current tile; one __syncthreads per K-step.
// EPI 0: relu(bn(acc+bias)) -> bf16 | EPI 1: acc+bias+resid -> bf16
// EPI 2: relu(bn(acc+bias)) -> col-max over tile rows, atomicMax into out
template <int EPI>
__global__ __launch_bounds__(256)
void gemm_k(const short* __restrict__ A, const short* __restrict__ BT,
            int K, int Nact,
            const float* __restrict__ bias, const float* __restrict__ gamma,
            const float* __restrict__ beta,
            short* __restrict__ outB, float* __restrict__ outF,
            const short* __restrict__ resid) {
    __shared__ short sA[2][128 * 32];
    __shared__ short sB[2][128 * 32];
    const int tid = threadIdx.x;
    const int lane = tid & 63;
    const int wave = tid >> 6;
    const int wm = wave & 1, wn = wave >> 1;
    const int lr = lane & 15, lq = lane >> 4;
    const long m0 = (long)blockIdx.x * 128;
    const long n0 = (long)blockIdx.y * 128;

    const int srow = (lane >> 2);
    const int sp8 = (lane & 3) * 8;

    auto stage = [&](int buf, int k0) {
#pragma unroll
        for (int c = 0; c < 2; c++) {
            int chunk = wave * 2 + c;
            int rr = chunk * 16 + srow;
            __builtin_amdgcn_global_load_lds(
                (gshort*)(A + (m0 + rr) * K + k0 + sp8),
                (lshort*)&sA[buf][chunk * 512], 16, 0, 0);
            __builtin_amdgcn_global_load_lds(
                (gshort*)(BT + (n0 + rr) * K + k0 + sp8),
                (lshort*)&sB[buf][chunk * 512], 16, 0, 0);
        }
    };

    floatx4 acc[4][4];
#pragma unroll
    for (int i = 0; i < 4; i++)
#pragma unroll
        for (int j = 0; j < 4; j++) acc[i][j] = (floatx4){0.f, 0.f, 0.f, 0.f};

    const int T = K >> 5;
    stage(0, 0);
    __syncthreads();
    int cur = 0;
    for (int t = 0; t < T; ++t) {
        if (t + 1 < T) stage(cur ^ 1, (t + 1) << 5);
        short8 af[4], bf[4];
#pragma unroll
        for (int i = 0; i < 4; i++)
            af[i] = *(const short8*)(&sA[cur][(wm * 64 + i * 16 + lr) * 32 + lq * 8]);
#pragma unroll
        for (int j = 0; j < 4; j++)
            bf[j] = *(const short8*)(&sB[cur][(wn * 64 + j * 16 + lr) * 32 + lq * 8]);
#pragma unroll
        for (int i = 0; i < 4; i++)
#pragma unroll
            for (int j = 0; j < 4; j++)
                acc[i][j] = __builtin_amdgcn_mfma_f32_16x16x32_bf16(af[i], bf[j],
                                                                    acc[i][j], 0, 0, 0);
        __syncthreads();
        cur ^= 1;
    }

#pragma unroll
    for (int j = 0; j < 4; j++) {
        long col = n0 + wn * 64 + j * 16 + lr;
        if (col >= Nact) continue;
        float bi = bias[col];
        float gs = 0.f, bt = 0.f;
        if (EPI != 1) { gs = gamma[col] * BN_SCALE; bt = beta[col]; }
        float colmax = 0.f;
#pragma unroll
        for (int i = 0; i < 4; i++) {
#pragma unroll
            for (int rg = 0; rg < 4; rg++) {
                long row = m0 + wm * 64 + i * 16 + lq * 4 + rg;
                float v = acc[i][j][rg];
                if (EPI == 1) {
                    v = v + bi + bf2f(resid[row * Nact + col]);
                    outB[row * Nact + col] = f2bf(v);
                } else {
                    v = fmaxf((v + bi) * gs + bt, 0.f);
                    if (EPI == 0) outB[row * Nact + col] = f2bf(v);
                    else colmax = fmaxf(colmax, v);
                }
            }
        }
        if (EPI == 2) {
            colmax = fmaxf(colmax, __shfl_xor(colmax, 16));
            colmax = fmaxf(colmax, __shfl_xor(colmax, 32));
            if (lq == 0) {
                int bb = (int)(m0 >> 11);
                atomicMax((unsigned int*)&outF[bb * 170 + col],
                          __float_as_uint(colmax));
            }
        }
    }
}

// largest float R with  (correctly-rounded sqrtf(R)) <= r :
// fl(sqrt(s)) <= r  <=>  sqrt(s) < midpoint(r, nextafter(r))  <=>  s < m^2
static inline float sq_thresh(float r) {
    double m = (double)r + ((double)nextafterf(r, 2.0f) - (double)r) * 0.5;
    double t = m * m;
    float R = (float)t;
    while ((double)R >= t) R = nextafterf(R, 0.0f);
    return R;
}

extern "C" void kernel_launch(void* const* d_in, const int* in_sizes, int n_in,
                              void* d_out, int out_size, void* d_ws, size_t ws_size,
                              hipStream_t stream) {
    const float* points = (const float*)d_in[0];
    const float* noise  = (const float*)d_in[1];
    const float* tw   = (const float*)d_in[2];
    const float* tb   = (const float*)d_in[3];
    const float* tg1  = (const float*)d_in[4];
    const float* tbt1 = (const float*)d_in[5];
    const float* td1w = (const float*)d_in[6];
    const float* td1b = (const float*)d_in[7];
    const float* tg2  = (const float*)d_in[8];
    const float* tbt2 = (const float*)d_in[9];
    const float* td2w = (const float*)d_in[10];
    const float* td2b = (const float*)d_in[11];
    const float* c1w  = (const float*)d_in[12];
    const float* c1b  = (const float*)d_in[13];
    const float* g1   = (const float*)d_in[14];
    const float* be1  = (const float*)d_in[15];
    const float* rw   = (const float*)d_in[16];
    const float* rb   = (const float*)d_in[17];
    const float* b1w  = (const float*)d_in[18];
    const float* b1b  = (const float*)d_in[19];
    const float* b1g  = (const float*)d_in[20];
    const float* b1be = (const float*)d_in[21];
    const float* b2w  = (const float*)d_in[22];
    const float* b2b  = (const float*)d_in[23];
    const float* b2g  = (const float*)d_in[24];
    const float* b2be = (const float*)d_in[25];
    const float* b3w  = (const float*)d_in[26];
    const float* b3b  = (const float*)d_in[27];
    const float* b3g  = (const float*)d_in[28];
    const float* b3be = (const float*)d_in[29];

    char* ws = (char*)d_ws;
    short* feats = (short*)(ws + OFF_FEATS);   // region0 (also f2, f4)
    short* f1    = (short*)(ws + OFF_R1);      // region1 (also f3)
    short* c1wT  = (short*)(ws + OFF_C1WT);
    short* rwT   = (short*)(ws + OFF_RWT);
    short* b1wT  = (short*)(ws + OFF_B1WT);
    short* b2wT  = (short*)(ws + OFF_B2WT);
    short* b3wT  = (short*)(ws + OFF_B3WT);
    float* pts   = (float*)(ws + OFF_PTS);
    float* part  = (float*)(ws + OFF_PART);
    float* outF  = (float*)d_out;

    const float r0s = sq_thresh(0.1f);
    const float r1s = sq_thresh(0.3f);
    const float r2s = sq_thresh(0.7f);

    init_k<<<313, 256, 0, stream>>>(c1w, rw, b1w, b2w, b3w,
                                    c1wT, rwT, b1wT, b2wT, b3wT,
                                    points, tw, tb, tg1, tbt1, part,
                                    outF, out_size);
    tnet2_k<<<8, 1024, 0, stream>>>(points, part, td1w, td1b, tg2, tbt2,
                                    td2w, td2b, pts);
    topk_feats_k<<<dim3(256, 8), 512, 0, stream>>>(pts, noise, feats,
                                                   r0s, r1s, r2s);

    gemm_k<0><<<dim3(128, 4), 256, 0, stream>>>(feats, c1wT, 576, 512, c1b, g1, be1,
                                                f1, nullptr, nullptr);
    gemm_k<1><<<dim3(128, 4), 256, 0, stream>>>(f1, rwT, 512, 512, rb, nullptr, nullptr,
                                                feats, nullptr, f1);
    gemm_k<0><<<dim3(128, 4), 256, 0, stream>>>(feats, b1wT, 512, 512, b1b, b1g, b1be,
                                                f1, nullptr, nullptr);
    gemm_k<0><<<dim3(128, 2), 256, 0, stream>>>(f1, b2wT, 512, 256, b2b, b2g, b2be,
                                                feats, nullptr, nullptr);
    gemm_k<2><<<dim3(128, 2), 256, 0, stream>>>(feats, b3wT, 256, 170, b3b, b3g, b3be,
                                                nullptr, outF, nullptr);
}

// Round 11
// 424.113 us; speedup vs baseline: 1.3360x; 1.0090x over previous
//
#include <hip/hip_runtime.h>
#include <hip/hip_bf16.h>
#include <math.h>

// ---------------------------------------------------------------------------
// PointCloudExtractor: T-Net -> transform -> multi-radius topK gather -> MLP
// B=8 N=2048 K=64 TU=256 U=512, blocks 512->512, 512->256, 256->170
// Pipeline: init(memset+convw_t+tnet1), tnet2, topk, 5x gemm  [R6 structure]
// R2:  topk insertion shift via DPP WF_SR1
// R3:  gemm 2-phase double-buffered staging
// R6:  fused init; topk 512-thr blocks
// R8:  decomposition: ~195us fixed harness, ~127 topk, ~85 gemms, ~18 rest
// R10: squared-distance thresholds (sqrt-free hot loop)  [best: 427.9 us]
// R11: topk noise prefetch deepened to 2 chunks (nnxt + nnxt2): R10 showed
//      VALUBusy DROP with the shorter body -> latency-exposed; ~half of
//      noise reads miss L3 (~900cy) and 1-chunk lookahead can't hide it.
// ---------------------------------------------------------------------------

#define BN_SCALE 0.99950037468777f   // float32(1/sqrt(1+1e-3))

typedef short short8 __attribute__((ext_vector_type(8)));
typedef float floatx4 __attribute__((ext_vector_type(4)));

typedef __attribute__((address_space(1))) const short gshort;
typedef __attribute__((address_space(3))) short lshort;

// workspace layout (bytes)
#define OFF_FEATS 0                      // bf16 [16384,576]  18,874,368 (region0)
#define OFF_R1    18874368               // region1 16,777,216: f1/f3 bf16 [16384,512]
#define OFF_W     (OFF_R1 + 16777216)
#define OFF_C1WT  (OFF_W)                // bf16 [512][576]
#define OFF_RWT   (OFF_C1WT + 589824)    // bf16 [512][512]
#define OFF_B1WT  (OFF_RWT + 524288)     // bf16 [512][512]
#define OFF_B2WT  (OFF_B1WT + 524288)    // bf16 [256][512]
#define OFF_B3WT  (OFF_B2WT + 262144)    // bf16 [256][256] (rows>=170 zero)
#define OFF_PTS   (OFF_B3WT + 131072)    // f32 [8,2048,3]
#define OFF_PART  (OFF_PTS + 196608)     // f32 [8][8][256] tnet1 partial max

__device__ inline short f2bf(float x) {
    __hip_bfloat16 h = __float2bfloat16(x);
    return *reinterpret_cast<short*>(&h);
}
__device__ inline float bf2f(short s) {
    return __uint_as_float(((unsigned)(unsigned short)s) << 16);
}

// ---- fused init: weight transpose (blocks 0..247) + T-Net layer1 partial
//      max (blocks 248..311) + d_out zero-init (block 312) -----------------
__global__ __launch_bounds__(256)
void init_k(const float* __restrict__ c1w, const float* __restrict__ rw,
            const float* __restrict__ b1w, const float* __restrict__ b2w,
            const float* __restrict__ b3w,
            short* __restrict__ c1wT, short* __restrict__ rwT,
            short* __restrict__ b1wT, short* __restrict__ b2wT,
            short* __restrict__ b3wT,
            const float* __restrict__ points, const float* __restrict__ tw,
            const float* __restrict__ tb, const float* __restrict__ tg1,
            const float* __restrict__ tbt1, float* __restrict__ part,
            float* __restrict__ outF, int out_n) {
    __shared__ float smem[64 * 65];
    const int bid = blockIdx.x;
    if (bid < 248) {
        float (*tile)[65] = (float(*)[65])smem;
        const float* src; short* dst; int K, N, t;
        if (bid < 72)       { src = c1w; dst = c1wT; K = 576; N = 512; t = bid; }
        else if (bid < 136) { src = rw;  dst = rwT;  K = 512; N = 512; t = bid - 72; }
        else if (bid < 200) { src = b1w; dst = b1wT; K = 512; N = 512; t = bid - 136; }
        else if (bid < 232) { src = b2w; dst = b2wT; K = 512; N = 256; t = bid - 200; }
        else                { src = b3w; dst = b3wT; K = 256; N = 170; t = bid - 232; }
        int ktiles = K >> 6;
        int k0 = (t % ktiles) * 64, n0 = (t / ktiles) * 64;
        int tx = threadIdx.x & 63, ty = threadIdx.x >> 6;
#pragma unroll
        for (int p = 0; p < 16; p++) {
            int r = p * 4 + ty;
            int n = n0 + tx;
            tile[r][tx] = (n < N) ? src[(size_t)(k0 + r) * N + n] : 0.f;
        }
        __syncthreads();
#pragma unroll
        for (int p = 0; p < 16; p++) {
            int r = p * 4 + ty;
            dst[(size_t)(n0 + r) * K + k0 + tx] = f2bf(tile[tx][r]);
        }
    } else if (bid < 312) {
        float* spts = smem;   // [768]
        const int t2 = bid - 248;
        const int chunk = t2 & 7, b = t2 >> 3;
        const int u = threadIdx.x;
        const float* pb = points + ((size_t)b * 2048 + chunk * 256) * 3;
        for (int i = u; i < 768; i += 256) spts[i] = pb[i];
        const float w0 = tw[u], w1 = tw[256 + u], w2 = tw[512 + u];
        const float bi = tb[u];
        const float gs = tg1[u] * BN_SCALE, bt = tbt1[u];
        __syncthreads();
        float m = 0.f;  // relu outputs >= 0
        for (int nn = 0; nn < 256; nn++) {
            float v = spts[nn * 3] * w0 + spts[nn * 3 + 1] * w1 +
                      spts[nn * 3 + 2] * w2 + bi;
            v = fmaxf(v * gs + bt, 0.f);
            m = fmaxf(m, v);
        }
        part[((b * 8 + chunk) << 8) + u] = m;
    } else {
        for (int i = threadIdx.x; i < out_n; i += 256) outF[i] = 0.f;
    }
}

// ---- T-Net dense layers + transform pts (latency-parallel matvecs) ---------
__global__ __launch_bounds__(1024)
void tnet2_k(const float* __restrict__ points, const float* __restrict__ part,
             const float* __restrict__ td1w, const float* __restrict__ td1b,
             const float* __restrict__ tg2, const float* __restrict__ tbt2,
             const float* __restrict__ td2w, const float* __restrict__ td2b,
             float* __restrict__ pts_out) {
    __shared__ float sx[256], sp[4][256], sx2[256], sp2[9][32], sT[9];
    const int b = blockIdx.x;
    const int tid = threadIdx.x;
    if (tid < 256) {
        float m = 0.f;
#pragma unroll
        for (int c = 0; c < 8; c++) m = fmaxf(m, part[((b * 8 + c) << 8) + tid]);
        sx[tid] = m;
    }
    __syncthreads();
    {
        int t = tid & 255, g = tid >> 8;
        float s = 0.f;
#pragma unroll 8
        for (int i = 0; i < 64; i++) {
            int v = g * 64 + i;
            s += sx[v] * td1w[v * 256 + t];
        }
        sp[g][t] = s;
    }
    __syncthreads();
    if (tid < 256) {
        float s = td1b[tid] + sp[0][tid] + sp[1][tid] + sp[2][tid] + sp[3][tid];
        sx2[tid] = fmaxf(s * (tg2[tid] * BN_SCALE) + tbt2[tid], 0.f);
    }
    __syncthreads();
    if (tid < 288) {
        int j = tid / 32, vg = tid & 31;
        float s = 0.f;
#pragma unroll
        for (int i = 0; i < 8; i++) {
            int v = vg * 8 + i;
            s += sx2[v] * td2w[v * 9 + j];
        }
        sp2[j][vg] = s;
    }
    __syncthreads();
    if (tid < 9) {
        float s = td2b[tid];
        for (int vg = 0; vg < 32; vg++) s += sp2[tid][vg];
        sT[tid] = s;
    }
    __syncthreads();
    for (int n = tid; n < 2048; n += 1024) {
        size_t idx = ((size_t)b * 2048 + n) * 3;
        float p0 = points[idx], p1 = points[idx + 1], p2 = points[idx + 2];
        pts_out[idx]     = p0 * sT[0] + p1 * sT[3] + p2 * sT[6];
        pts_out[idx + 1] = p0 * sT[1] + p1 * sT[4] + p2 * sT[7];
        pts_out[idx + 2] = p0 * sT[2] + p1 * sT[5] + p2 * sT[8];
    }
}

// ---- top-K ball query + gather -> feats bf16 -------------------------------
// Squared-distance thresholds (host-computed, exact). Insertion via DPP
// WF_SR1. R11: noise prefetched two chunks ahead (nnxt, nnxt2).
__device__ inline unsigned dpp_shr1(unsigned v) {
    return (unsigned)__builtin_amdgcn_update_dpp(0, (int)v, 0x138 /*WF_SR1*/,
                                                 0xF, 0xF, false);
}

__device__ inline void ins_one(unsigned& llo, unsigned& lhi, unsigned vlo,
                               unsigned vhi, int lane) {
    unsigned long long lv = ((unsigned long long)lhi << 32) | llo;
    unsigned long long vv = ((unsigned long long)vhi << 32) | vlo;
    unsigned long long ltm = __ballot(lv < vv);
    if (ltm) {
        int p = __builtin_ctzll(ltm);
        unsigned uplo = dpp_shr1(llo);
        unsigned uphi = dpp_shr1(lhi);
        if (lane >= p) {
            llo = (lane == p) ? vlo : uplo;
            lhi = (lane == p) ? vhi : uphi;
        }
    }
}

__device__ inline void run_q(unsigned& llo, unsigned& lhi, unsigned long long& th,
                             unsigned klo, unsigned khi, unsigned long long qual,
                             int lane) {
    do {
        int src = __builtin_ctzll(qual);
        qual &= qual - 1;
        unsigned vlo = (unsigned)__builtin_amdgcn_readlane((int)klo, src);
        unsigned vhi = (unsigned)__builtin_amdgcn_readlane((int)khi, src);
        ins_one(llo, lhi, vlo, vhi, lane);
    } while (qual);
    th = ((unsigned long long)(unsigned)__builtin_amdgcn_readlane((int)lhi, 63) << 32)
         | (unsigned)__builtin_amdgcn_readlane((int)llo, 63);
}

__device__ inline void init_radius(bool in, unsigned nb, unsigned klo, int lane,
                                   unsigned& llo, unsigned& lhi,
                                   unsigned long long& th) {
    unsigned long long inm = __ballot(in);
    int S = 64 - __builtin_popcountll(inm);
    int mbI = __builtin_amdgcn_mbcnt_hi((unsigned)(inm >> 32),
              __builtin_amdgcn_mbcnt_lo((unsigned)inm, 0));
    int mbS = lane - mbI;
    int dst = in ? (S + mbI) : mbS;
    llo = (unsigned)__builtin_amdgcn_ds_permute(dst << 2, in ? 0 : (int)klo);
    lhi = 0;
    if (inm) {
        do {
            int src = __builtin_ctzll(inm);
            inm &= inm - 1;
            unsigned vlo = (unsigned)__builtin_amdgcn_readlane((int)klo, src);
            unsigned vhi = (unsigned)__builtin_amdgcn_readlane((int)nb, src);
            ins_one(llo, lhi, vlo, vhi, lane);
        } while (inm);
    }
    th = ((unsigned long long)(unsigned)__builtin_amdgcn_readlane((int)lhi, 63) << 32)
         | (unsigned)__builtin_amdgcn_readlane((int)llo, 63);
}

__global__ __launch_bounds__(512)
void topk_feats_k(const float* __restrict__ pts, const float* __restrict__ noise,
                  short* __restrict__ feats,
                  float r0s, float r1s, float r2s) {
    __shared__ float sxp[2048], syp[2048], szp[2048];
    const int b = blockIdx.y;
    const int tid = threadIdx.x;
    const int lane = tid & 63;
    const int wave = tid >> 6;
    const int n = blockIdx.x * 8 + wave;
    const float* nrow = noise + ((size_t)b * 2048 + n) * 2048;
    float ncur  = nrow[lane];
    float nnxt  = nrow[64 + lane];
    float nnxt2 = nrow[128 + lane];
    for (int i = tid; i < 2048; i += 512) {
        size_t p = ((size_t)b * 2048 + i) * 3;
        sxp[i] = pts[p];
        syp[i] = pts[p + 1];
        szp[i] = pts[p + 2];
    }
    __syncthreads();
    const float qx = sxp[n], qy = syp[n], qz = szp[n];

    unsigned L0lo, L0hi, L1lo, L1hi, L2lo, L2hi;
    unsigned long long th0, th1, th2;
    {
        float dx = qx - sxp[lane], dy = qy - syp[lane], dz = qz - szp[lane];
        float s = dx * dx + dy * dy + dz * dz;
        unsigned nb = __float_as_uint(ncur);
        unsigned klo = 2047 - lane;
        init_radius(s <= r0s, nb, klo, lane, L0lo, L0hi, th0);
        init_radius(s <= r1s, nb, klo, lane, L1lo, L1hi, th1);
        init_radius(s <= r2s, nb, klo, lane, L2lo, L2hi, th2);
    }
    for (int base = 64; base < 2048; base += 64) {
        float cur = nnxt;
        nnxt = nnxt2;
        if (base + 128 < 2048) nnxt2 = nrow[base + 128 + lane];
        const int j = base + lane;
        float dx = qx - sxp[j], dy = qy - syp[j], dz = qz - szp[j];
        float s = dx * dx + dy * dy + dz * dz;
        unsigned nb = __float_as_uint(cur);
        unsigned klo = 2047 - j;
        unsigned k0hi = (s <= r0s) ? nb : 0u;
        unsigned k1hi = (s <= r1s) ? nb : 0u;
        unsigned k2hi = (s <= r2s) ? nb : 0u;
        unsigned long long key0 = ((unsigned long long)k0hi << 32) | klo;
        unsigned long long key1 = ((unsigned long long)k1hi << 32) | klo;
        unsigned long long key2 = ((unsigned long long)k2hi << 32) | klo;
        unsigned long long q0 = __ballot(key0 > th0);
        unsigned long long q1 = __ballot(key1 > th1);
        unsigned long long q2 = __ballot(key2 > th2);
        if (q0) run_q(L0lo, L0hi, th0, klo, k0hi, q0, lane);
        if (q1) run_q(L1lo, L1hi, th1, klo, k1hi, q1, lane);
        if (q2) run_q(L2lo, L2hi, th2, klo, k2hi, q2, lane);
    }
    size_t basef = ((size_t)b * 2048 + n) * 576 + (size_t)lane * 9;
    int j0 = 2047 - (int)(L0lo & 0x7FFu);
    int j1 = 2047 - (int)(L1lo & 0x7FFu);
    int j2 = 2047 - (int)(L2lo & 0x7FFu);
    feats[basef + 0] = f2bf(sxp[j0]);
    feats[basef + 1] = f2bf(syp[j0]);
    feats[basef + 2] = f2bf(szp[j0]);
    feats[basef + 3] = f2bf(sxp[j1]);
    feats[basef + 4] = f2bf(syp[j1]);
    feats[basef + 5] = f2bf(szp[j1]);
    feats[basef + 6] = f2bf(sxp[j2]);
    feats[basef + 7] = f2bf(syp[j2]);
    feats[basef + 8] = f2bf(szp[j2]);
}

// ---- bf16 MFMA GEMM, 128x128 tile, 4 waves, 2-phase double-buffered --------
template <int EPI>
__global__ __launch_bounds__(256)
void gemm_k(const short* __restrict__ A, const short* __restrict__ BT,
            int K, int Nact,
            const float* __restrict__ bias, const float* __restrict__ gamma,
            const float* __restrict__ beta,
            short* __restrict__ outB, float* __restrict__ outF,
            const short* __restrict__ resid) {
    __shared__ short sA[2][128 * 32];
    __shared__ short sB[2][128 * 32];
    const int tid = threadIdx.x;
    const int lane = tid & 63;
    const int wave = tid >> 6;
    const int wm = wave & 1, wn = wave >> 1;
    const int lr = lane & 15, lq = lane >> 4;
    const long m0 = (long)blockIdx.x * 128;
    const long n0 = (long)blockIdx.y * 128;

    const int srow = (lane >> 2);
    const int sp8 = (lane & 3) * 8;

    auto stage = [&](int buf, int k0) {
#pragma unroll
        for (int c = 0; c < 2; c++) {
            int chunk = wave * 2 + c;
            int rr = chunk * 16 + srow;
            __builtin_amdgcn_global_load_lds(
                (gshort*)(A + (m0 + rr) * K + k0 + sp8),
                (lshort*)&sA[buf][chunk * 512], 16, 0, 0);
            __builtin_amdgcn_global_load_lds(
                (gshort*)(BT + (n0 + rr) * K + k0 + sp8),
                (lshort*)&sB[buf][chunk * 512], 16, 0, 0);
        }
    };

    floatx4 acc[4][4];
#pragma unroll
    for (int i = 0; i < 4; i++)
#pragma unroll
        for (int j = 0; j < 4; j++) acc[i][j] = (floatx4){0.f, 0.f, 0.f, 0.f};

    const int T = K >> 5;
    stage(0, 0);
    __syncthreads();
    int cur = 0;
    for (int t = 0; t < T; ++t) {
        if (t + 1 < T) stage(cur ^ 1, (t + 1) << 5);
        short8 af[4], bf[4];
#pragma unroll
        for (int i = 0; i < 4; i++)
            af[i] = *(const short8*)(&sA[cur][(wm * 64 + i * 16 + lr) * 32 + lq * 8]);
#pragma unroll
        for (int j = 0; j < 4; j++)
            bf[j] = *(const short8*)(&sB[cur][(wn * 64 + j * 16 + lr) * 32 + lq * 8]);
#pragma unroll
        for (int i = 0; i < 4; i++)
#pragma unroll
            for (int j = 0; j < 4; j++)
                acc[i][j] = __builtin_amdgcn_mfma_f32_16x16x32_bf16(af[i], bf[j],
                                                                    acc[i][j], 0, 0, 0);
        __syncthreads();
        cur ^= 1;
    }

#pragma unroll
    for (int j = 0; j < 4; j++) {
        long col = n0 + wn * 64 + j * 16 + lr;
        if (col >= Nact) continue;
        float bi = bias[col];
        float gs = 0.f, bt = 0.f;
        if (EPI != 1) { gs = gamma[col] * BN_SCALE; bt = beta[col]; }
        float colmax = 0.f;
#pragma unroll
        for (int i = 0; i < 4; i++) {
#pragma unroll
            for (int rg = 0; rg < 4; rg++) {
                long row = m0 + wm * 64 + i * 16 + lq * 4 + rg;
                float v = acc[i][j][rg];
                if (EPI == 1) {
                    v = v + bi + bf2f(resid[row * Nact + col]);
                    outB[row * Nact + col] = f2bf(v);
                } else {
                    v = fmaxf((v + bi) * gs + bt, 0.f);
                    if (EPI == 0) outB[row * Nact + col] = f2bf(v);
                    else colmax = fmaxf(colmax, v);
                }
            }
        }
        if (EPI == 2) {
            colmax = fmaxf(colmax, __shfl_xor(colmax, 16));
            colmax = fmaxf(colmax, __shfl_xor(colmax, 32));
            if (lq == 0) {
                int bb = (int)(m0 >> 11);
                atomicMax((unsigned int*)&outF[bb * 170 + col],
                          __float_as_uint(colmax));
            }
        }
    }
}

// largest float R with  (correctly-rounded sqrtf(R)) <= r :
// fl(sqrt(s)) <= r  <=>  sqrt(s) < midpoint(r, nextafter(r))  <=>  s < m^2
static inline float sq_thresh(float r) {
    double m = (double)r + ((double)nextafterf(r, 2.0f) - (double)r) * 0.5;
    double t = m * m;
    float R = (float)t;
    while ((double)R >= t) R = nextafterf(R, 0.0f);
    return R;
}

extern "C" void kernel_launch(void* const* d_in, const int* in_sizes, int n_in,
                              void* d_out, int out_size, void* d_ws, size_t ws_size,
                              hipStream_t stream) {
    const float* points = (const float*)d_in[0];
    const float* noise  = (const float*)d_in[1];
    const float* tw   = (const float*)d_in[2];
    const float* tb   = (const float*)d_in[3];
    const float* tg1  = (const float*)d_in[4];
    const float* tbt1 = (const float*)d_in[5];
    const float* td1w = (const float*)d_in[6];
    const float* td1b = (const float*)d_in[7];
    const float* tg2  = (const float*)d_in[8];
    const float* tbt2 = (const float*)d_in[9];
    const float* td2w = (const float*)d_in[10];
    const float* td2b = (const float*)d_in[11];
    const float* c1w  = (const float*)d_in[12];
    const float* c1b  = (const float*)d_in[13];
    const float* g1   = (const float*)d_in[14];
    const float* be1  = (const float*)d_in[15];
    const float* rw   = (const float*)d_in[16];
    const float* rb   = (const float*)d_in[17];
    const float* b1w  = (const float*)d_in[18];
    const float* b1b  = (const float*)d_in[19];
    const float* b1g  = (const float*)d_in[20];
    const float* b1be = (const float*)d_in[21];
    const float* b2w  = (const float*)d_in[22];
    const float* b2b  = (const float*)d_in[23];
    const float* b2g  = (const float*)d_in[24];
    const float* b2be = (const float*)d_in[25];
    const float* b3w  = (const float*)d_in[26];
    const float* b3b  = (const float*)d_in[27];
    const float* b3g  = (const float*)d_in[28];
    const float* b3be = (const float*)d_in[29];

    char* ws = (char*)d_ws;
    short* feats = (short*)(ws + OFF_FEATS);   // region0 (also f2, f4)
    short* f1    = (short*)(ws + OFF_R1);      // region1 (also f3)
    short* c1wT  = (short*)(ws + OFF_C1WT);
    short* rwT   = (short*)(ws + OFF_RWT);
    short* b1wT  = (short*)(ws + OFF_B1WT);
    short* b2wT  = (short*)(ws + OFF_B2WT);
    short* b3wT  = (short*)(ws + OFF_B3WT);
    float* pts   = (float*)(ws + OFF_PTS);
    float* part  = (float*)(ws + OFF_PART);
    float* outF  = (float*)d_out;

    const float r0s = sq_thresh(0.1f);
    const float r1s = sq_thresh(0.3f);
    const float r2s = sq_thresh(0.7f);

    init_k<<<313, 256, 0, stream>>>(c1w, rw, b1w, b2w, b3w,
                                    c1wT, rwT, b1wT, b2wT, b3wT,
                                    points, tw, tb, tg1, tbt1, part,
                                    outF, out_size);
    tnet2_k<<<8, 1024, 0, stream>>>(points, part, td1w, td1b, tg2, tbt2,
                                    td2w, td2b, pts);
    topk_feats_k<<<dim3(256, 8), 512, 0, stream>>>(pts, noise, feats,
                                                   r0s, r1s, r2s);

    gemm_k<0><<<dim3(128, 4), 256, 0, stream>>>(feats, c1wT, 576, 512, c1b, g1, be1,
                                                f1, nullptr, nullptr);
    gemm_k<1><<<dim3(128, 4), 256, 0, stream>>>(f1, rwT, 512, 512, rb, nullptr, nullptr,
                                                feats, nullptr, f1);
    gemm_k<0><<<dim3(128, 4), 256, 0, stream>>>(feats, b1wT, 512, 512, b1b, b1g, b1be,
                                                f1, nullptr, nullptr);
    gemm_k<0><<<dim3(128, 2), 256, 0, stream>>>(f1, b2wT, 512, 256, b2b, b2g, b2be,
                                                feats, nullptr, nullptr);
    gemm_k<2><<<dim3(128, 2), 256, 0, stream>>>(feats, b3wT, 256, 170, b3b, b3g, b3be,
                                                nullptr, outF, nullptr);
}